// Round 1
// baseline (206.855 us; speedup 1.0000x reference)
//
#include <hip/hip_runtime.h>
#include <hip/hip_bf16.h>
#include <stdint.h>

#define BATCH 64
#define CIN   64
#define LEN   4096
#define COUT  128
#define KW    7
#define LPOOL 2048

typedef __bf16 v8bf __attribute__((ext_vector_type(8)));
typedef float  v4f  __attribute__((ext_vector_type(4)));

// Convert conv_w [COUT][CIN][KW] fp32 -> Wt [KW][COUT][CIN] bf16 (RNE).
__global__ __launch_bounds__(256)
void wconv_kernel(const float* __restrict__ W, ushort* __restrict__ Wt) {
    int i = blockIdx.x * 256 + threadIdx.x;
    if (i >= COUT * CIN * KW) return;
    int co  = i / (CIN * KW);
    int rem = i - co * (CIN * KW);
    int ci  = rem / KW;
    int k   = rem - ci * KW;
    uint u = __float_as_uint(W[i]);
    uint r = (u + 0x7FFFu + ((u >> 16) & 1u)) >> 16;   // RNE to bf16
    Wt[(k * COUT + co) * CIN + ci] = (ushort)r;
}

// Fused: BN -> sign -> conv (bf16 MFMA) -> alpha -> PReLU -> maxpool2.
// Block: 256 threads (4 waves). Tile: 64 l-positions x all 128 couts for one batch.
// Wave w: couts [32w, 32w+32) (2 n-tiles) x 4 m-tiles (l). 8 accum tiles/wave.
__global__ __launch_bounds__(256)
void conv_kernel(const float* __restrict__ I,
                 const float* __restrict__ bn_g, const float* __restrict__ bn_b,
                 const float* __restrict__ bn_m, const float* __restrict__ bn_v,
                 const ushort* __restrict__ Wt,
                 const float* __restrict__ alpha, const float* __restrict__ prelu,
                 float* __restrict__ out) {
    // staging: 70 rows x 72 ushorts (144B pitch, 16B-aligned reads, 2-way banks) = 10080B
    // epilogue: 128 x 36 floats (144B pitch) = 18432B. Same buffer, separated by barriers.
    __shared__ __align__(16) char lds_raw[18432];
    ushort* stg = (ushort*)lds_raw;
    float*  ep  = (float*)lds_raw;
    __shared__ float sc_s[CIN], mu_s[CIN], be_s[CIN];

    int tid = threadIdx.x;
    int b = blockIdx.y, l0 = blockIdx.x * 64;

    if (tid < CIN) {
        // bit-exact vs np fp32: gamma / sqrt(var + eps)
        float s = __fdiv_rn(bn_g[tid], __fsqrt_rn(__fadd_rn(bn_v[tid], 1e-5f)));
        sc_s[tid] = s; mu_s[tid] = bn_m[tid]; be_s[tid] = bn_b[tid];
    }
    __syncthreads();

    // Stage binarized signs: stg[r][ci] = sign(bn(I[b][ci][l0-3+r])), r in [0,70)
    const float* Ib = I + (size_t)b * CIN * LEN;
    for (int i = tid; i < CIN * 70; i += 256) {
        int ci = i / 70;
        int r  = i - ci * 70;
        int p  = l0 - 3 + r;
        ushort s = 0;
        if (p >= 0 && p < LEN) {
            float v = Ib[ci * LEN + p];
            // (v - mean) * scale + beta, no fp-contraction (sign boundary must match np)
            float x = __fadd_rn(__fmul_rn(__fsub_rn(v, mu_s[ci]), sc_s[ci]), be_s[ci]);
            s = x > 0.f ? (ushort)0x3F80 : (x < 0.f ? (ushort)0xBF80 : (ushort)0);
        }
        stg[r * 72 + ci] = s;
    }
    __syncthreads();

    int lane = tid & 63, wave = tid >> 6;
    int quad = lane >> 4, lr = lane & 15;
    int cout0 = wave * 32;

    v4f acc[4][2];
    #pragma unroll
    for (int mt = 0; mt < 4; ++mt) { acc[mt][0] = (v4f)0.f; acc[mt][1] = (v4f)0.f; }

    for (int k = 0; k < KW; ++k) {
        #pragma unroll
        for (int h = 0; h < 2; ++h) {
            int cibase = h * 32 + quad * 8;
            // B-frag (weights): B[kk=quad*8+j][n=lr] = W[cout0+n][ci=cibase+j]
            const ushort* wrow = Wt + ((size_t)(k * COUT) + cout0 + lr) * CIN + cibase;
            v8bf bf0 = *(const v8bf*)(wrow);
            v8bf bf1 = *(const v8bf*)(wrow + 16 * CIN);
            #pragma unroll
            for (int mt = 0; mt < 4; ++mt) {
                // A-frag (signs): A[m=lr][kk=quad*8+j] from row (l_local + k)
                v8bf a = *(const v8bf*)(stg + (mt * 16 + lr + k) * 72 + cibase);
                acc[mt][0] = __builtin_amdgcn_mfma_f32_16x16x32_bf16(a, bf0, acc[mt][0], 0, 0, 0);
                acc[mt][1] = __builtin_amdgcn_mfma_f32_16x16x32_bf16(a, bf1, acc[mt][1], 0, 0, 0);
            }
        }
    }
    __syncthreads();   // done reading stg; reuse LDS for epilogue

    // alpha * PReLU, then in-lane pool: quad holds l = mt*16 + quad*4 + {0..3}
    float pw = prelu[0];
    #pragma unroll
    for (int nt = 0; nt < 2; ++nt) {
        int co = cout0 + nt * 16 + lr;
        float al = alpha[co];
        #pragma unroll
        for (int mt = 0; mt < 4; ++mt) {
            float v0 = acc[mt][nt][0] * al; v0 = v0 > 0.f ? v0 : pw * v0;
            float v1 = acc[mt][nt][1] * al; v1 = v1 > 0.f ? v1 : pw * v1;
            float v2 = acc[mt][nt][2] * al; v2 = v2 > 0.f ? v2 : pw * v2;
            float v3 = acc[mt][nt][3] * al; v3 = v3 > 0.f ? v3 : pw * v3;
            int lp = mt * 8 + quad * 2;
            ep[co * 36 + lp]     = fmaxf(v0, v1);
            ep[co * 36 + lp + 1] = fmaxf(v2, v3);
        }
    }
    __syncthreads();

    // Coalesced float4 stores: out[b][co][blockIdx.x*32 + 0..31]
    float* ob = out + ((size_t)b * COUT) * LPOOL + blockIdx.x * 32;
    for (int i = tid; i < COUT * 8; i += 256) {
        int co = i >> 3, c4 = i & 7;
        *(float4*)(ob + (size_t)co * LPOOL + c4 * 4) = *(const float4*)(ep + co * 36 + c4 * 4);
    }
}

extern "C" void kernel_launch(void* const* d_in, const int* in_sizes, int n_in,
                              void* d_out, int out_size, void* d_ws, size_t ws_size,
                              hipStream_t stream) {
    const float* I      = (const float*)d_in[0];
    const float* bn_g   = (const float*)d_in[1];
    const float* bn_b   = (const float*)d_in[2];
    const float* bn_m   = (const float*)d_in[3];
    const float* bn_v   = (const float*)d_in[4];
    const float* conv_w = (const float*)d_in[5];
    const float* alpha  = (const float*)d_in[6];
    const float* prelu  = (const float*)d_in[7];
    float* out = (float*)d_out;

    ushort* Wt = (ushort*)d_ws;   // 7*128*64*2 = 114688 bytes

    wconv_kernel<<<(COUT * CIN * KW + 255) / 256, 256, 0, stream>>>(conv_w, Wt);
    dim3 grid(LEN / 64, BATCH);
    conv_kernel<<<grid, 256, 0, stream>>>(I, bn_g, bn_b, bn_m, bn_v, Wt, alpha, prelu, out);
}

// Round 2
// 187.001 us; speedup vs baseline: 1.1062x; 1.1062x over previous
//
#include <hip/hip_runtime.h>
#include <hip/hip_bf16.h>
#include <stdint.h>

#define BATCH 64
#define CIN   64
#define LEN   4096
#define COUT  128
#define KW    7
#define LPOOL 2048
#define RROWS 72   // staged halo rows: p = l0-4+r, r in [0,72)

typedef __bf16 v8bf __attribute__((ext_vector_type(8)));
typedef unsigned short v8us __attribute__((ext_vector_type(8)));
typedef float  v4f  __attribute__((ext_vector_type(4)));

// Convert conv_w [COUT][CIN][KW] fp32 -> Wt [KW][COUT][CIN] bf16 (RNE).
__global__ __launch_bounds__(256)
void wconv_kernel(const float* __restrict__ W, ushort* __restrict__ Wt) {
    int i = blockIdx.x * 256 + threadIdx.x;
    if (i >= COUT * CIN * KW) return;
    int co  = i / (CIN * KW);
    int rem = i - co * (CIN * KW);
    int ci  = rem / KW;
    int k   = rem - ci * KW;
    uint u = __float_as_uint(W[i]);
    uint r = (u + 0x7FFFu + ((u >> 16) & 1u)) >> 16;   // RNE to bf16
    Wt[(k * COUT + co) * CIN + ci] = (ushort)r;
}

// Fused: BN -> sign -> conv (bf16 MFMA) -> alpha -> PReLU -> maxpool2.
// Block: 256 threads (4 waves). Tile: 64 l x 128 cout x 1 batch.
// Staging: thread owns ci-group g=tid>>5 (8 ci), rows r=(tid&31)+32*it.
//   8 coalesced scalar loads per row -> 8 signs -> ONE ds_write_b128.
//   Bank pattern: dword = 36r + 4g -> all 32 banks evenly, 8 dw/bank = b128 floor.
__global__ __launch_bounds__(256, 4)
void conv_kernel(const float* __restrict__ I,
                 const float* __restrict__ bn_g, const float* __restrict__ bn_b,
                 const float* __restrict__ bn_m, const float* __restrict__ bn_v,
                 const ushort* __restrict__ Wt,
                 const float* __restrict__ alpha, const float* __restrict__ prelu,
                 float* __restrict__ out) {
    __shared__ __align__(16) ushort stg[RROWS * 72];   // pitch 72 ushorts = 144B
    __shared__ float4 bnc[CIN];                         // (scale, mean, beta, -)

    int tid = threadIdx.x;
    int b = blockIdx.y, l0 = blockIdx.x * 64;

    if (tid < CIN) {
        // bit-exact vs np fp32: gamma / sqrt(var + eps)
        float s = __fdiv_rn(bn_g[tid], __fsqrt_rn(__fadd_rn(bn_v[tid], 1e-5f)));
        bnc[tid] = make_float4(s, bn_m[tid], bn_b[tid], 0.f);
    }
    __syncthreads();

    // ---- staging ----
    int g = tid >> 5;          // ci-group (8 ci), 0..7
    int rbase = tid & 31;
    float sc[8], mu[8], be[8];
    #pragma unroll
    for (int j = 0; j < 8; ++j) {
        float4 c = bnc[8 * g + j];
        sc[j] = c.x; mu[j] = c.y; be[j] = c.z;
    }

    const float* Ib = I + (size_t)b * CIN * LEN + (size_t)g * 8 * LEN;
    float v[3][8];
    bool inb[3];
    #pragma unroll
    for (int it = 0; it < 3; ++it) {
        int r = rbase + 32 * it;
        int p = l0 - 4 + r;
        inb[it] = (r < RROWS) && (p >= 0) && (p < LEN);
        #pragma unroll
        for (int j = 0; j < 8; ++j)
            v[it][j] = inb[it] ? Ib[j * LEN + p] : 0.f;
    }
    #pragma unroll
    for (int it = 0; it < 3; ++it) {
        int r = rbase + 32 * it;
        if (r < RROWS) {
            v8us u;
            #pragma unroll
            for (int j = 0; j < 8; ++j) {
                // (v - mean) * scale + beta, exact np rounding (sign boundary)
                float x = __fadd_rn(__fmul_rn(__fsub_rn(v[it][j], mu[j]), sc[j]), be[j]);
                ushort s = x > 0.f ? (ushort)0x3F80 : (x < 0.f ? (ushort)0xBF80 : (ushort)0);
                if (!inb[it]) s = 0;
                u[j] = s;
            }
            *(v8us*)(stg + r * 72 + g * 8) = u;
        }
    }
    __syncthreads();

    // ---- MFMA ----
    int lane = tid & 63, wave = tid >> 6;
    int quad = lane >> 4, lr = lane & 15;
    int cout0 = wave * 32;

    v4f acc[4][2];
    #pragma unroll
    for (int mt = 0; mt < 4; ++mt) { acc[mt][0] = (v4f)0.f; acc[mt][1] = (v4f)0.f; }

    #pragma unroll
    for (int k = 0; k < KW; ++k) {
        #pragma unroll
        for (int h = 0; h < 2; ++h) {
            int cibase = h * 32 + quad * 8;
            const ushort* wrow = Wt + ((size_t)(k * COUT) + cout0 + lr) * CIN + cibase;
            v8bf b0 = *(const v8bf*)(wrow);
            v8bf b1 = *(const v8bf*)(wrow + 16 * CIN);
            #pragma unroll
            for (int mt = 0; mt < 4; ++mt) {
                // A row for output l=mt*16+lr at tap k: r = l + k + 1
                v8bf a = *(const v8bf*)(stg + (mt * 16 + lr + k + 1) * 72 + cibase);
                acc[mt][0] = __builtin_amdgcn_mfma_f32_16x16x32_bf16(a, b0, acc[mt][0], 0, 0, 0);
                acc[mt][1] = __builtin_amdgcn_mfma_f32_16x16x32_bf16(a, b1, acc[mt][1], 0, 0, 0);
            }
        }
    }

    // ---- epilogue: alpha * PReLU, in-lane pool, direct global float2 stores ----
    // quad holds l = mt*16 + quad*4 + {0..3} -> pooled lp = mt*8 + quad*2 + {0,1}
    float pw = prelu[0];
    float* ob = out + ((size_t)b * COUT) * LPOOL + blockIdx.x * 32;
    #pragma unroll
    for (int nt = 0; nt < 2; ++nt) {
        int co = cout0 + nt * 16 + lr;
        float al = alpha[co];
        float* oc = ob + (size_t)co * LPOOL + quad * 2;
        #pragma unroll
        for (int mt = 0; mt < 4; ++mt) {
            float v0 = acc[mt][nt][0] * al; v0 = v0 > 0.f ? v0 : pw * v0;
            float v1 = acc[mt][nt][1] * al; v1 = v1 > 0.f ? v1 : pw * v1;
            float v2 = acc[mt][nt][2] * al; v2 = v2 > 0.f ? v2 : pw * v2;
            float v3 = acc[mt][nt][3] * al; v3 = v3 > 0.f ? v3 : pw * v3;
            *(float2*)(oc + mt * 8) = make_float2(fmaxf(v0, v1), fmaxf(v2, v3));
        }
    }
}

extern "C" void kernel_launch(void* const* d_in, const int* in_sizes, int n_in,
                              void* d_out, int out_size, void* d_ws, size_t ws_size,
                              hipStream_t stream) {
    const float* I      = (const float*)d_in[0];
    const float* bn_g   = (const float*)d_in[1];
    const float* bn_b   = (const float*)d_in[2];
    const float* bn_m   = (const float*)d_in[3];
    const float* bn_v   = (const float*)d_in[4];
    const float* conv_w = (const float*)d_in[5];
    const float* alpha  = (const float*)d_in[6];
    const float* prelu  = (const float*)d_in[7];
    float* out = (float*)d_out;

    ushort* Wt = (ushort*)d_ws;   // 7*128*64*2 = 114688 bytes

    wconv_kernel<<<(COUT * CIN * KW + 255) / 256, 256, 0, stream>>>(conv_w, Wt);
    dim3 grid(LEN / 64, BATCH);
    conv_kernel<<<grid, 256, 0, stream>>>(I, bn_g, bn_b, bn_m, bn_v, Wt, alpha, prelu, out);
}